// Round 1
// baseline (256.011 us; speedup 1.0000x reference)
//
#include <hip/hip_runtime.h>

// HungarianCELoss — analytic collapse of the 120-perm matching.
// targets has only 2 distinct rows (fg, bg=1-fg), so cost[b,k,j] has only
// 2 distinct values per (b,k); argmin over perms == argmin_k (cost_fg-cost_bg),
// ties -> smallest k (matches lex order of itertools.permutations).
// BCE sum = sum A[b,k] - sum_b C[b,k*], with
//   A = sum_n softplus(x) - x*(1-fg),  C = sum_n x*(2fg-1),
//   inter_fg = sum_n sigmoid(x)*fg,    S = sum_n sigmoid(x),  Tf = sum_n fg.

#define BB 64
#define KK 5
#define NPIX 102400   // 320*320
#define CHUNKS 25
#define CHUNK_PIX 4096
#define THREADS 256
#define NV 21
#define STRIDE 24     // padded record stride in floats

__global__ __launch_bounds__(THREADS) void hung_pass1(
    const float* __restrict__ slot,   // (B,K,N)
    const float* __restrict__ tgt,    // (B,1,N)
    float* __restrict__ ws)           // (CHUNKS, B, STRIDE)
{
    const int b  = blockIdx.y;
    const int cx = blockIdx.x;
    const float* t  = tgt  + (size_t)b * NPIX;
    const float* xb = slot + (size_t)b * KK * NPIX;

    float A[KK] = {0,0,0,0,0};
    float C[KK] = {0,0,0,0,0};
    float I[KK] = {0,0,0,0,0};
    float S[KK] = {0,0,0,0,0};
    float Tf = 0.0f;

    const int base = cx * CHUNK_PIX;
    #pragma unroll
    for (int it = 0; it < CHUNK_PIX / (THREADS * 4); ++it) {
        const int pix = base + it * (THREADS * 4) + threadIdx.x * 4;
        const float4 fg4 = *reinterpret_cast<const float4*>(t + pix);
        Tf += (fg4.x + fg4.y) + (fg4.z + fg4.w);
        float fgv[4] = {fg4.x, fg4.y, fg4.z, fg4.w};
        #pragma unroll
        for (int k = 0; k < KK; ++k) {
            const float4 x4 = *reinterpret_cast<const float4*>(xb + (size_t)k * NPIX + pix);
            float xv[4] = {x4.x, x4.y, x4.z, x4.w};
            #pragma unroll
            for (int j = 0; j < 4; ++j) {
                const float x  = xv[j];
                const float fg = fgv[j];
                const float e   = __expf(-fabsf(x));
                const float inv = __builtin_amdgcn_rcpf(1.0f + e);
                const float s   = (x >= 0.0f) ? inv : e * inv;       // sigmoid(x)
                const float sp  = fmaxf(x, 0.0f) + __logf(1.0f + e); // stable softplus pieces
                A[k] += sp - x * (1.0f - fg);
                C[k] += x * (2.0f * fg - 1.0f);
                I[k] += s * fg;
                S[k] += s;
            }
        }
    }

    float vals[NV];
    #pragma unroll
    for (int k = 0; k < KK; ++k) {
        vals[k]      = A[k];
        vals[5 + k]  = C[k];
        vals[10 + k] = I[k];
        vals[15 + k] = S[k];
    }
    vals[20] = Tf;

    // wave(64)-level shuffle reduce, then 4-wave LDS combine
    #pragma unroll
    for (int j = 0; j < NV; ++j) {
        float v = vals[j];
        #pragma unroll
        for (int off = 32; off > 0; off >>= 1) v += __shfl_down(v, off, 64);
        vals[j] = v;
    }
    __shared__ float red[THREADS / 64][NV];
    const int lane = threadIdx.x & 63;
    const int wv   = threadIdx.x >> 6;
    if (lane == 0) {
        #pragma unroll
        for (int j = 0; j < NV; ++j) red[wv][j] = vals[j];
    }
    __syncthreads();
    if (threadIdx.x < NV) {
        const float sum = red[0][threadIdx.x] + red[1][threadIdx.x]
                        + red[2][threadIdx.x] + red[3][threadIdx.x];
        ws[((size_t)(cx * BB + b)) * STRIDE + threadIdx.x] = sum;
    }
}

__global__ __launch_bounds__(64) void hung_pass2(
    const float* __restrict__ ws, float* __restrict__ out)
{
    const int b = threadIdx.x;  // one image per lane, single wave
    float v[NV];
    #pragma unroll
    for (int j = 0; j < NV; ++j) v[j] = 0.0f;
    for (int c = 0; c < CHUNKS; ++c) {
        const float* p = ws + ((size_t)(c * BB + b)) * STRIDE;
        #pragma unroll
        for (int j = 0; j < NV; ++j) v[j] += p[j];
    }
    const float Tf = v[20];
    const float Tb = (float)NPIX - Tf;
    float best = 3.402823466e+38f;
    int   kb   = 0;
    float sumA = 0.0f;
    #pragma unroll
    for (int k = 0; k < KK; ++k) {
        const float Iv = v[10 + k], Sv = v[15 + k];
        const float cf = 1.0f - Iv / (Sv + Tf - Iv + 1e-6f);
        const float Ib = Sv - Iv;
        const float cb = 1.0f - Ib / (Sv + Tb - Ib + 1e-6f);
        const float d  = cf - cb;
        if (d < best) { best = d; kb = k; }   // strict < : ties -> smallest k
        sumA += v[k];
    }
    float tot = sumA - v[5 + kb];
    #pragma unroll
    for (int off = 32; off > 0; off >>= 1) tot += __shfl_down(tot, off, 64);
    if (b == 0) out[0] = tot * (1.0f / ((float)BB * (float)KK * (float)NPIX));
}

extern "C" void kernel_launch(void* const* d_in, const int* in_sizes, int n_in,
                              void* d_out, int out_size, void* d_ws, size_t ws_size,
                              hipStream_t stream) {
    // setup_inputs order: fg_logits (unused by reference), slot_logits, target
    const float* slot = (const float*)d_in[1];
    const float* tgt  = (const float*)d_in[2];
    float* out = (float*)d_out;
    float* ws  = (float*)d_ws;

    dim3 grid(CHUNKS, BB);
    hung_pass1<<<grid, THREADS, 0, stream>>>(slot, tgt, ws);
    hung_pass2<<<1, 64, 0, stream>>>(ws, out);
}